// Round 25
// baseline (164.110 us; speedup 1.0000x reference)
//
#include <hip/hip_runtime.h>
#include <hip/hip_bf16.h>

// Sizes
// B=8, N=1024, S=16, C=3, H=8, DIM=768, HD=96, SCALE=96^-0.5, BN_EPS=1e-3
//
// Algebraic restructuring (R5): out = BN(P@W_re)@V collapses to
//   out[n][d] = sum_m P[n][m] * M2[m][d] + cv[d]
//   M2[m][d]  = sum_p W_re[m][p] * G[p] * V[p][d]      (12.9 GF, batched bh)
//   cv[d]     = sum_p Cc[p] * V[p][d]
// R25: conv __launch_bounds__(256) (no min-waves) — R24 showed conv pinned at
//      the 128-VGPR cap (demand ~190: 144-reg row file + pk[24]), forcing the
//      allocator to serialize the 36 row loads. Uncapped, the loads pipeline
//      (ILP replaces TLP). Everything else identical to R24.

typedef __attribute__((ext_vector_type(4))) float f32x4;
typedef __bf16 __attribute__((ext_vector_type(8))) bf16x8;
typedef unsigned short u16x8 __attribute__((ext_vector_type(8)));
typedef unsigned int u32x4 __attribute__((ext_vector_type(4)));

__device__ __forceinline__ unsigned short f2bf(float x){
  unsigned u = __builtin_bit_cast(unsigned, x);
  u += 0x7fffu + ((u >> 16) & 1u);          // round-to-nearest-even
  return (unsigned short)(u >> 16);
}

// compiler-lowered conversion (fuses to v_cvt_pk_bf16_f32 for pairs)
__device__ __forceinline__ unsigned short f2bfc(float x){
  __hip_bfloat16 h = __float2bfloat16(x);
  return __builtin_bit_cast(unsigned short, h);
}

__device__ __forceinline__ float bf2f(unsigned short u){
  unsigned v = (unsigned)u << 16;
  return __builtin_bit_cast(float, v);
}

__device__ __forceinline__ f32x4 mfma16(bf16x8 a, bf16x8 b, f32x4 c){
  return __builtin_amdgcn_mfma_f32_16x16x32_bf16(a, b, c, 0, 0, 0);
}

__device__ __forceinline__ bf16x8 ld8(const unsigned short* p){
  return *reinterpret_cast<const bf16x8*>(p);
}

// ---------------------------------------------------------------------------
// Prep: Wre_rm[m][p] = bf16(w_re[m][p]) (coalesced cast);
//       G[p] = gamma*rsqrt(var+eps); Cc=(b_re-mean)*G+beta; CoverG=Cc/G
// ---------------------------------------------------------------------------
__global__ void prep_kernel(const float* __restrict__ w_re, const float* __restrict__ b_re,
                            const float* __restrict__ gma, const float* __restrict__ beta,
                            const float* __restrict__ mean, const float* __restrict__ var,
                            unsigned short* __restrict__ Wre_rm,
                            float* __restrict__ G, float* __restrict__ Cc,
                            float* __restrict__ CoverG)
{
  int idx = blockIdx.x * 256 + threadIdx.x;
  if (idx < 1024*1024){
    Wre_rm[idx] = f2bf(w_re[idx]);
  } else if (idx < 1024*1024 + 1024){
    int p = idx - 1024*1024;
    float g = gma[p] * rsqrtf(var[p] + 1e-3f);
    float cc = (b_re[p] - mean[p]) * g + beta[p];
    G[p] = g;
    Cc[p] = cc;
    CoverG[p] = cc / g;
  }
}

// ---------------------------------------------------------------------------
// Wpt[o][i] = bf16(w_proj[i][o]) via LDS 64x64 tiles (coalesced both sides)
// ---------------------------------------------------------------------------
__global__ __launch_bounds__(256) void wpt_kernel(const float* __restrict__ wp,
                                                  unsigned short* __restrict__ Wpt)
{
  __shared__ float t[64][65];
  const int i0 = blockIdx.x * 64, o0 = blockIdx.y * 64;
  const int r = threadIdx.x >> 6;        // 0..3
  const int c = threadIdx.x & 63;        // 0..63
#pragma unroll
  for (int rep = 0; rep < 16; ++rep){
    int row = rep*4 + r;
    t[row][c] = wp[(size_t)(i0 + row)*768 + o0 + c];
  }
  __syncthreads();
#pragma unroll
  for (int rep = 0; rep < 16; ++rep){
    int orow = rep*4 + r;
    Wpt[(size_t)(o0 + orow)*768 + i0 + c] = f2bf(t[c][orow]);
  }
}

// ---------------------------------------------------------------------------
// Conv 3x3 SAME (R17 structure, R25: uncapped registers); row-per-thread,
// 16 tokens/block, NO LDS. 36 dwordx4 row loads pipeline in ~190 VGPRs.
// Interleaved convert-and-pack keeps pk[24] as the only extra live range.
// Weights SGPR-resident.
// ---------------------------------------------------------------------------
__global__ __launch_bounds__(256) void conv_kernel(
    const float* __restrict__ q, const float* __restrict__ k,
    const float* __restrict__ v,
    const float* __restrict__ wq, const float* __restrict__ wk,
    const float* __restrict__ wv,
    const float* __restrict__ G,
    unsigned short* __restrict__ qh, unsigned short* __restrict__ kh,
    unsigned short* __restrict__ vh)
{
  const int tb = blockIdx.x;         // 0..511 (16 tokens each)
  const int which = blockIdx.y;      // 0=q 1=k 2=v
  const float* x = (which == 0) ? q : (which == 1) ? k : v;
  const float* w = (which == 0) ? wq : (which == 1) ? wk : wv;
  unsigned short* dst = (which == 0) ? qh : (which == 1) ? kh : vh;

  // weights -> SGPRs (uniform pointer, compile-time offsets => s_load)
  float wreg[81];
#pragma unroll
  for (int i = 0; i < 81; ++i) wreg[i] = w[i];

  const int tid = threadIdx.x;
  const int ti = tid >> 4;           // token in block 0..15
  const int r  = tid & 15;           // output row 0..15
  const int token = tb*16 + ti;
  const float* xt = x + (size_t)token*768;

  const int rm = (r > 0)  ? r-1 : 0;
  const int rp = (r < 15) ? r+1 : 15;
  const float mm = (r > 0)  ? 1.f : 0.f;
  const float mp = (r < 15) ? 1.f : 0.f;

  f32x4 Rm[12], R0[12], Rp[12];
#pragma unroll
  for (int j = 0; j < 12; ++j){
    Rm[j] = *reinterpret_cast<const f32x4*>(xt + rm*48 + j*4);
    R0[j] = *reinterpret_cast<const f32x4*>(xt + r *48 + j*4);
    Rp[j] = *reinterpret_cast<const f32x4*>(xt + rp*48 + j*4);
  }
#pragma unroll
  for (int j = 0; j < 12; ++j){
    Rm[j] = Rm[j] * mm;
    Rp[j] = Rp[j] * mp;
  }

  const float gs = (which == 2) ? G[token & 1023] : 1.f;

  unsigned int pk[24];               // 48 u16 packed as 24 dwords

#pragma unroll
  for (int c = 0; c < 16; ++c){
    float a0 = 0.f, a1 = 0.f, a2 = 0.f;
#pragma unroll
    for (int dc = 0; dc < 3; ++dc){
      const int cc = c + dc - 1;
      if (cc < 0 || cc > 15) continue;         // static skip (halo)
#pragma unroll
      for (int ci = 0; ci < 3; ++ci){
        const int e = cc*3 + ci;
        const float xm = Rm[e >> 2][e & 3];
        const float x0 = R0[e >> 2][e & 3];
        const float xp = Rp[e >> 2][e & 3];
        const int w0 = (0*3 + dc)*9 + ci*3;
        const int w1 = (1*3 + dc)*9 + ci*3;
        const int w2 = (2*3 + dc)*9 + ci*3;
        a0 += xm*wreg[w0+0] + x0*wreg[w1+0] + xp*wreg[w2+0];
        a1 += xm*wreg[w0+1] + x0*wreg[w1+1] + xp*wreg[w2+1];
        a2 += xm*wreg[w0+2] + x0*wreg[w1+2] + xp*wreg[w2+2];
      }
    }
    const unsigned short b0 = f2bf(a0*gs), b1 = f2bf(a1*gs), b2 = f2bf(a2*gs);
    const int f = c*3;               // 0,3,6,...,45 (u16 index in [0,48))
    if ((f & 1) == 0){
      pk[f>>1] = (unsigned)b0 | ((unsigned)b1 << 16);
      pk[(f+2)>>1] = (unsigned)b2;                     // low half; high set later
    } else {
      pk[f>>1] |= ((unsigned)b0 << 16);
      pk[(f+1)>>1] = (unsigned)b1 | ((unsigned)b2 << 16);
    }
  }

  const int b = token >> 10, n = token & 1023;
  const int h = r >> 1;
  unsigned short* dstp = dst + ((size_t)(b*8 + h)*1024 + n)*96 + (r & 1)*48;
#pragma unroll
  for (int j = 0; j < 6; ++j){
    u32x4 sv;
#pragma unroll
    for (int e = 0; e < 4; ++e) sv[e] = pk[j*4 + e];
    *reinterpret_cast<u32x4*>(dstp + j*8) = sv;        // 8 u16 = 16 B per store
  }
}

// ---------------------------------------------------------------------------
// Transpose vh[bh][n][96] -> vtg[bh][d][n] via LDS tile; also accumulates
// cvpart[chunk][bh][d]. Grid (8 n-chunks, 64 bh).
// ---------------------------------------------------------------------------
__global__ __launch_bounds__(256) void vt_kernel(const unsigned short* __restrict__ vh,
                                                 const float* __restrict__ CoverG,
                                                 unsigned short* __restrict__ vtg,
                                                 float* __restrict__ cvpart)
{
  __shared__ unsigned short t[96*136];       // row d: stride 136 (272 B, 16B-aligned, odd*16B)
  const int chunk = blockIdx.x;              // 0..7
  const int bh = blockIdx.y;                 // 0..63
  const int n0 = chunk*128;
  const int tid = threadIdx.x;

  const unsigned short* src = vh + ((size_t)bh*1024 + n0)*96;
#pragma unroll
  for (int it = 0; it < 6; ++it){
    int idx = it*256 + tid;                  // 0..1535
    int row = idx / 12, v = idx - row*12;    // row 0..127, v 0..11
    u16x8 xv = *reinterpret_cast<const u16x8*>(src + row*96 + v*8);
#pragma unroll
    for (int j = 0; j < 8; ++j) t[(v*8 + j)*136 + row] = xv[j];
  }
  __syncthreads();

  unsigned short* dstp = vtg + (size_t)bh*96*1024 + n0;
#pragma unroll
  for (int it = 0; it < 6; ++it){
    int idx = it*256 + tid;                  // 0..1535
    int d = idx >> 4, ch = idx & 15;         // d 0..95, ch 0..15
    u16x8 xv = *reinterpret_cast<const u16x8*>(&t[d*136 + ch*8]);
    *reinterpret_cast<u16x8*>(dstp + (size_t)d*1024 + ch*8) = xv;

    // cv partial: this thread holds V[d][n0+ch*8 .. +8)
    float s = 0.f;
#pragma unroll
    for (int j = 0; j < 8; ++j) s += CoverG[n0 + ch*8 + j] * bf2f(xv[j]);
#pragma unroll
    for (int o = 1; o < 16; o <<= 1) s += __shfl_xor(s, o);   // reduce 16-lane group
    if (ch == 0) cvpart[((size_t)chunk*64 + bh)*96 + d] = s;
  }
}

// ---------------------------------------------------------------------------
// M2t[bh][d][m] = sum_p Wre_rm[m][p] * vtg[bh][d][p]   (K = 1024 over p)
// R11: block-staged double-buffered W-tile (128x32) + V-tile (96x32).
// ---------------------------------------------------------------------------
__global__ __launch_bounds__(256, 2) void m2_kernel(
    const unsigned short* __restrict__ Wre_rm, const unsigned short* __restrict__ vtg,
    unsigned short* __restrict__ M2t)
{
  constexpr int WST = 40;   // W-tile row stride (u16): 128 x 40
  constexpr int VST = 40;   // V-tile row stride (u16): 96 x 40
  __shared__ __align__(16) unsigned short Wst[2][128*WST];   // 20480 B
  __shared__ __align__(16) unsigned short Vst[2][96*VST];    // 15360 B -> 35840 B

  const int id = blockIdx.x;             // 0..511
  const int xcd = id & 7, slot = id >> 3;
  const int mtile = slot & 7;            // 0..7
  const int bh = xcd + ((slot >> 3) << 3);
  const int tid = threadIdx.x;
  const int w = tid >> 6, lane = tid & 63, lh = lane >> 4, lm = lane & 15;
  const int m0 = mtile*128;              // block's m-base
  const int mw = w*32;                   // wave's m offset in tile

  const unsigned short* vb = vtg + (size_t)bh * 96 * 1024;
  const unsigned short* Wb = Wre_rm + (size_t)m0 * 1024;

  const int cr = tid >> 2, cc0 = (tid & 3)*8;
  const bool has3 = (tid < 128);

  f32x4 acc[2][6];
#pragma unroll
  for (int rt = 0; rt < 2; ++rt)
#pragma unroll
    for (int dt = 0; dt < 6; ++dt)
      acc[rt][dt] = f32x4{0.f, 0.f, 0.f, 0.f};

  // --- prologue: stage p-tile 0 into buffer 0 ---
  u16x8 g0, g1, g2, g3;
  g0 = *reinterpret_cast<const u16x8*>(Wb + (size_t)cr*1024 + cc0);
  g1 = *reinterpret_cast<const u16x8*>(Wb + (size_t)(64 + cr)*1024 + cc0);
  g2 = *reinterpret_cast<const u16x8*>(vb + (size_t)cr*1024 + cc0);
  if (has3) g3 = *reinterpret_cast<const u16x8*>(vb + (size_t)(64 + cr)*1024 + cc0);
  *reinterpret_cast<u16x8*>(&Wst[0][cr*WST + cc0]) = g0;
  *reinterpret_cast<u16x8*>(&Wst[0][(64 + cr)*WST + cc0]) = g1;
  *reinterpret_cast<u16x8*>(&Vst[0][cr*VST + cc0]) = g2;
  if (has3) *reinterpret_cast<u16x8*>(&Vst[0][(64 + cr)*VST + cc0]) = g3;
  __syncthreads();

  for (int ks = 0; ks < 32; ++ks){
    const int cur = ks & 1;

    if (ks < 31){
      const int p0 = (ks+1)*32;
      g0 = *reinterpret_cast<const u16x8*>(Wb + (size_t)cr*1024 + p0 + cc0);
      g1 = *reinterpret_cast<const u16x8*>(Wb + (size_t)(64 + cr)*1024 + p0 + cc0);
      g2 = *reinterpret_cast<const u16x8*>(vb + (size_t)cr*1024 + p0 + cc0);
      if (has3) g3 = *reinterpret_cast<const u16x8*>(vb + (size_t)(64 + cr)*1024 + p0 + cc0);
    }

    const unsigned short* Wc = &Wst[cur][0];
    const unsigned short* Vc = &Vst[cur][0];
    bf16x8 aW0 = ld8(Wc + (mw + lm)*WST + lh*8);
    bf16x8 aW1 = ld8(Wc + (mw + 16 + lm)*WST + lh*8);
#pragma unroll
    for (int dt = 0; dt < 6; ++dt){
      bf16x8 bV = ld8(Vc + (dt*16 + lm)*VST + lh*8);
      acc[0][dt] = mfma16(aW0, bV, acc[0][dt]);
      acc[1][dt] = mfma16(aW1, bV, acc[1][dt]);
    }

    if (ks < 31){
      const int nxt = cur ^ 1;
      *reinterpret_cast<u16x8*>(&Wst[nxt][cr*WST + cc0]) = g0;
      *reinterpret_cast<u16x8*>(&Wst[nxt][(64 + cr)*WST + cc0]) = g1;
      *reinterpret_cast<u16x8*>(&Vst[nxt][cr*VST + cc0]) = g2;
      if (has3) *reinterpret_cast<u16x8*>(&Vst[nxt][(64 + cr)*VST + cc0]) = g3;
    }
    __syncthreads();
  }

#pragma unroll
  for (int rt = 0; rt < 2; ++rt)
#pragma unroll
    for (int dt = 0; dt < 6; ++dt)
#pragma unroll
      for (int rg = 0; rg < 4; ++rg){
        int m = m0 + mw + rt*16 + lh*4 + rg;
        int d = dt*16 + lm;
        M2t[((size_t)bh*96 + d)*1024 + m] = f2bf(acc[rt][dt][rg]);
      }
}

// ---------------------------------------------------------------------------
// Fused attention (R22 config): 512 blocks (2/CU), 128 q-rows/block,
// 32 rows/wave. Block-staged K/M2 tiles (dbuf); single-buffered wave-private
// P stage; rowsum via ones-B MFMA; exp2 softmax; cv from 8 partials.
// ---------------------------------------------------------------------------
__global__ __launch_bounds__(256, 2) void attn_kernel(
    const unsigned short* __restrict__ qh, const unsigned short* __restrict__ kh,
    const unsigned short* __restrict__ M2t, const float* __restrict__ cvpart,
    unsigned short* __restrict__ xh)
{
  constexpr int KST = 104;   // K-tile row stride (u16): 32 x 104
  constexpr int MST = 40;    // M-tile row stride (u16): 96 x 40
  constexpr int PST = 40;    // P stage row stride (u16): 32 x 40 per wave
  __shared__ __align__(16) unsigned short Kst[2][32*KST];    // 13312 B
  __shared__ __align__(16) unsigned short Mst[2][96*MST];    // 15360 B
  __shared__ __align__(16) unsigned short Pst[4][32*PST];    // 10240 B -> 38912 B

  const int id = blockIdx.x;             // 0..511
  const int xcd = id & 7, slot = id >> 3;
  const int chunk = slot & 7;            // 128-row chunk
  const int bh = xcd + ((slot >> 3) << 3);
  const int tid = threadIdx.x;
  const int w = tid >> 6;                // 0..3
  const int lane = tid & 63;
  const int lh = lane >> 4;              // 0..3
  const int lm = lane & 15;              // 0..15
  const int q0 = chunk*128 + w*32;       // this wave's 32 q-rows

  const unsigned short* Qb = qh + (size_t)bh * 1024 * 96;
  const unsigned short* Kb = kh + (size_t)bh * 1024 * 96;
  const unsigned short* Mb = M2t + (size_t)bh * 96 * 1024;

  const int kr0 = tid/12,  kc0 = (tid%12)*8;
  const bool c1K = (tid < 128);
  const int t1 = tid + 256;
  const int kr1 = c1K ? t1/12 : 0,  kc1 = c1K ? (t1%12)*8 : 0;
  const int md1 = c1K ? 0 : (tid-128)>>2, mc1 = c1K ? 0 : ((tid-128)&3)*8;
  const int md2 = (tid+128)>>2, mc2 = ((tid+128)&3)*8;

  bf16x8 aq[2][3];
#pragma unroll
  for (int rt = 0; rt < 2; ++rt)
#pragma unroll
    for (int kq = 0; kq < 3; ++kq)
      aq[rt][kq] = ld8(Qb + (size_t)(q0 + rt*16 + lm)*96 + kq*32 + lh*8);

  // ones B-fragment for the rowsum MFMA (bf16 1.0 = 0x3F80)
  u16x8 onesU = {0x3F80, 0x3F80, 0x3F80, 0x3F80, 0x3F80, 0x3F80, 0x3F80, 0x3F80};
  const bf16x8 kOnes = __builtin_bit_cast(bf16x8, onesU);

  f32x4 out[2][6];
#pragma unroll
  for (int rt = 0; rt < 2; ++rt)
#pragma unroll
    for (int dt = 0; dt < 6; ++dt) out[rt][dt] = f32x4{0.f, 0.f, 0.f, 0.f};
  f32x4 outS[2] = {f32x4{0.f,0.f,0.f,0.f}, f32x4{0.f,0.f,0.f,0.f}};

  // SCALE * log2(e): exp(x*SCALE) = exp2(x*SCALE2), native v_exp_f32
  const float SCALE2 = 0.14724404930696491f;

  u16x8 g0, g1, g2;
  {
    g0 = *reinterpret_cast<const u16x8*>(Kb + (size_t)kr0*96 + kc0);
    g1 = c1K ? *reinterpret_cast<const u16x8*>(Kb + (size_t)kr1*96 + kc1)
             : *reinterpret_cast<const u16x8*>(Mb + (size_t)md1*1024 + mc1);
    g2 = *reinterpret_cast<const u16x8*>(Mb + (size_t)md2*1024 + mc2);
    *reinterpret_cast<u16x8*>(&Kst[0][kr0*KST + kc0]) = g0;
    if (c1K) *reinterpret_cast<u16x8*>(&Kst[0][kr1*KST + kc1]) = g1;
    else     *reinterpret_cast<u16x8*>(&Mst[0][md1*MST + mc1]) = g1;
    *reinterpret_cast<u16x8*>(&Mst[0][md2*MST + mc2]) = g2;
  }
  __syncthreads();

  for (int kt = 0; kt < 32; ++kt){
    const int cur = kt & 1;

    if (kt < 31){
      const int kb = (kt+1)*32;
      g0 = *reinterpret_cast<const u16x8*>(Kb + (size_t)(kb + kr0)*96 + kc0);
      g1 = c1K ? *reinterpret_cast<const u16x8*>(Kb + (size_t)(kb + kr1)*96 + kc1)
               : *reinterpret_cast<const u16x8*>(Mb + (size_t)md1*1024 + kb + mc1);
      g2 = *reinterpret_cast<const u16x8*>(Mb + (size_t)md2*1024 + kb + mc2);
    }

    const unsigned short* Kc = &Kst[cur][0];
    f32x4 sacc[2][2];
    sacc[0][0] = f32x4{0.f,0.f,0.f,0.f}; sacc[0][1] = f32x4{0.f,0.f,0.f,0.f};
    sacc[1][0] = f32x4{0.f,0.f,0.f,0.f}; sacc[1][1] = f32x4{0.f,0.f,0.f,0.f};
#pragma unroll
    for (int kq = 0; kq < 3; ++kq){
      bf16x8 bk0 = ld8(Kc + lm*KST        + kq*32 + lh*8);
      bf16x8 bk1 = ld8(Kc + (16 + lm)*KST + kq*32 + lh*8);
      sacc[0][0] = mfma16(aq[0][kq], bk0, sacc[0][0]);
      sacc[0][1] = mfma16(aq[0][kq], bk1, sacc[0][1]);
      sacc[1][0] = mfma16(aq[1][kq], bk0, sacc[1][0]);
      sacc[1][1] = mfma16(aq[1][kq], bk1, sacc[1][1]);
    }

    // exp2 (unnormalized softmax) -> per-wave private P stage (single buffer)
    unsigned short* Pc = &Pst[w][0];
#pragma unroll
    for (int rt = 0; rt < 2; ++rt)
#pragma unroll
      for (int nt = 0; nt < 2; ++nt)
#pragma unroll
        for (int rg = 0; rg < 4; ++rg){
          float e = __builtin_amdgcn_exp2f(sacc[rt][nt][rg] * SCALE2);
          Pc[(rt*16 + lh*4 + rg)*PST + nt*16 + lm] = f2bfc(e);
        }

    bf16x8 ap0 = ld8(Pc + lm*PST        + lh*8);
    bf16x8 ap1 = ld8(Pc + (16 + lm)*PST + lh*8);

    // PV + rowsum (ones-B MFMA rides the matrix pipe)
    const unsigned short* Mc = &Mst[cur][0];
#pragma unroll
    for (int dt = 0; dt < 6; ++dt){
      bf16x8 bm = ld8(Mc + (dt*16 + lm)*MST + lh*8);
      out[0][dt] = mfma16(ap0, bm, out[0][dt]);
      out[1][dt] = mfma16(ap1, bm, out[1][dt]);
    }
    outS[0] = mfma16(ap0, kOnes, outS[0]);
    outS[1] = mfma16(ap1, kOnes, outS[1]);

    if (kt < 31){
      const int nxt = cur ^ 1;
      *reinterpret_cast<u16x8*>(&Kst[nxt][kr0*KST + kc0]) = g0;
      if (c1K) *reinterpret_cast<u16x8*>(&Kst[nxt][kr1*KST + kc1]) = g1;
      else     *reinterpret_cast<u16x8*>(&Mst[nxt][md1*MST + mc1]) = g1;
      *reinterpret_cast<u16x8*>(&Mst[nxt][md2*MST + mc2]) = g2;
    }
    __syncthreads();
  }

  // rowsum lives in outS: every lane's column holds the same row-sum
  f32x4 rinv[2];
#pragma unroll
  for (int rt = 0; rt < 2; ++rt)
#pragma unroll
    for (int rg = 0; rg < 4; ++rg)
      rinv[rt][rg] = 1.f / outS[rt][rg];

#pragma unroll
  for (int dt = 0; dt < 6; ++dt){
    float cvv = 0.f;
#pragma unroll
    for (int ch = 0; ch < 8; ++ch)
      cvv += cvpart[((size_t)ch*64 + bh)*96 + dt*16 + lm];
#pragma unroll
    for (int rt = 0; rt < 2; ++rt)
#pragma unroll
      for (int rg = 0; rg < 4; ++rg){
        int row = q0 + rt*16 + lh*4 + rg;
        xh[((size_t)bh*1024 + row)*96 + dt*16 + lm] =
            f2bfc(out[rt][dt][rg]*rinv[rt][rg] + cvv);
      }
  }
}

// ---------------------------------------------------------------------------
// Projection (R10): out[t][o] = sum_i xh[t][i]*Wpt[o][i] + b_proj[o].
// ---------------------------------------------------------------------------
__global__ __launch_bounds__(256, 2) void proj_kernel(
    const unsigned short* __restrict__ xh, const unsigned short* __restrict__ Wpt,
    const float* __restrict__ b_proj, float* __restrict__ out)
{
  constexpr int BST = 40;    // B-tile row stride (u16): 96 x 40
  __shared__ __align__(16) unsigned short Bst[2][96*BST];    // 15360 B

  const int mb = blockIdx.x;        // 0..63 -> 128 tokens
  const int nb = blockIdx.y;        // 0..7  -> 96 outputs
  const int tid = threadIdx.x;
  const int w = tid >> 6, lane = tid & 63, lh = lane >> 4, lm = lane & 15;
  const int t0 = mb*128 + w*32;
  const int o0 = nb*96;

  const int br0 = tid >> 2,          bc0 = (tid & 3)*8;
  const bool has1 = (tid < 128);
  const int br1 = (tid + 256) >> 2,  bc1 = ((tid + 256) & 3)*8;
  const unsigned short* Bsrc = Wpt + (size_t)o0*768;

  f32x4 acc[2][6];
#pragma unroll
  for (int rt = 0; rt < 2; ++rt)
#pragma unroll
    for (int nt = 0; nt < 6; ++nt) acc[rt][nt] = f32x4{0.f, 0.f, 0.f, 0.f};

  const int tok0 = t0 + lm, tok1 = t0 + 16 + lm;
  const int b0 = tok0 >> 10, n0_ = tok0 & 1023;
  const int b1 = tok1 >> 10, n1_ = tok1 & 1023;

  u16x8 g0, g1;
  g0 = *reinterpret_cast<const u16x8*>(Bsrc + (size_t)br0*768 + bc0);
  if (has1) g1 = *reinterpret_cast<const u16x8*>(Bsrc + (size_t)br1*768 + bc1);
  *reinterpret_cast<u16x8*>(&Bst[0][br0*BST + bc0]) = g0;
  if (has1) *reinterpret_cast<u16x8*>(&Bst[0][br1*BST + bc1]) = g1;
  __syncthreads();

  for (int kt = 0; kt < 24; ++kt){
    const int cur = kt & 1;

    if (kt < 23){
      const int ib = (kt+1)*32;
      g0 = *reinterpret_cast<const u16x8*>(Bsrc + (size_t)br0*768 + ib + bc0);
      if (has1) g1 = *reinterpret_cast<const u16x8*>(Bsrc + (size_t)br1*768 + ib + bc1);
    }

    const int h = kt/3, d0 = (kt - h*3)*32 + lh*8;
    bf16x8 a0 = ld8(xh + ((size_t)(b0*8 + h)*1024 + n0_)*96 + d0);
    bf16x8 a1 = ld8(xh + ((size_t)(b1*8 + h)*1024 + n1_)*96 + d0);

    const unsigned short* Bc = &Bst[cur][0];
#pragma unroll
    for (int nt = 0; nt < 6; ++nt){
      bf16x8 bv = ld8(Bc + (nt*16 + lm)*BST + lh*8);
      acc[0][nt] = mfma16(a0, bv, acc[0][nt]);
      acc[1][nt] = mfma16(a1, bv, acc[1][nt]);
    }

    if (kt < 23){
      const int nxt = cur ^ 1;
      *reinterpret_cast<u16x8*>(&Bst[nxt][br0*BST + bc0]) = g0;
      if (has1) *reinterpret_cast<u16x8*>(&Bst[nxt][br1*BST + bc1]) = g1;
    }
    __syncthreads();
  }

#pragma unroll
  for (int nt = 0; nt < 6; ++nt){
    int o = o0 + nt*16 + lm;
    float bias = b_proj[o];
#pragma unroll
    for (int rt = 0; rt < 2; ++rt)
#pragma unroll
      for (int rg = 0; rg < 4; ++rg)
        out[(size_t)(t0 + rt*16 + lh*4 + rg)*768 + o] = acc[rt][nt][rg] + bias;
  }
}

// ---------------------------------------------------------------------------
extern "C" void kernel_launch(void* const* d_in, const int* in_sizes, int n_in,
                              void* d_out, int out_size, void* d_ws, size_t ws_size,
                              hipStream_t stream)
{
  (void)in_sizes; (void)n_in; (void)out_size; (void)ws_size;
  const float* q      = (const float*)d_in[0];
  const float* k      = (const float*)d_in[1];
  const float* v      = (const float*)d_in[2];
  const float* wq     = (const float*)d_in[3];
  const float* wk     = (const float*)d_in[4];
  const float* wv     = (const float*)d_in[5];
  const float* w_re   = (const float*)d_in[6];
  const float* b_re   = (const float*)d_in[7];
  const float* gma    = (const float*)d_in[8];
  const float* beta   = (const float*)d_in[9];
  const float* mean   = (const float*)d_in[10];
  const float* var    = (const float*)d_in[11];
  const float* w_proj = (const float*)d_in[12];
  const float* b_proj = (const float*)d_in[13];
  float* out = (float*)d_out;

  // ws layout (bytes): total ~66.5 MB. vh aliases the xh slot (vh is dead
  // before attn writes xh).
  char* ws = (char*)d_ws;
  unsigned short* qh     = (unsigned short*)(ws + 0);          // 12,582,912
  unsigned short* kh     = (unsigned short*)(ws + 12582912);   // 12,582,912
  unsigned short* vtg    = (unsigned short*)(ws + 25165824);   // 12,582,912
  unsigned short* xh     = (unsigned short*)(ws + 37748736);   // 12,582,912
  unsigned short* vh     = xh;                                 // alias (dead before attn)
  unsigned short* Wre_rm = (unsigned short*)(ws + 50331648);   //  2,097,152
  unsigned short* Wpt    = (unsigned short*)(ws + 52428800);   //  1,179,648
  unsigned short* M2t    = (unsigned short*)(ws + 53608448);   // 12,582,912
  float*          G      = (float*)(ws + 66191360);            //      4,096
  float*          Cc     = (float*)(ws + 66195456);            //      4,096
  float*          CoverG = (float*)(ws + 66199552);            //      4,096
  float*          cvpart = (float*)(ws + 66203648);            //    196,608

  prep_kernel<<<dim3(4100), dim3(256), 0, stream>>>(w_re, b_re, gma, beta, mean, var,
                                                    Wre_rm, G, Cc, CoverG);
  wpt_kernel<<<dim3(12, 12), dim3(256), 0, stream>>>(w_proj, Wpt);
  conv_kernel<<<dim3(512, 3), dim3(256), 0, stream>>>(q, k, v, wq, wk, wv, G, qh, kh, vh);
  vt_kernel<<<dim3(8, 64), dim3(256), 0, stream>>>(vh, CoverG, vtg, cvpart);
  m2_kernel<<<dim3(512), dim3(256), 0, stream>>>(Wre_rm, vtg, M2t);
  attn_kernel<<<dim3(512), dim3(256), 0, stream>>>(qh, kh, M2t, cvpart, xh);
  proj_kernel<<<dim3(64, 8), dim3(256), 0, stream>>>(xh, Wpt, b_proj, out);
}

// Round 26
// 142.010 us; speedup vs baseline: 1.1556x; 1.1556x over previous
//
#include <hip/hip_runtime.h>
#include <hip/hip_bf16.h>

// Sizes
// B=8, N=1024, S=16, C=3, H=8, DIM=768, HD=96, SCALE=96^-0.5, BN_EPS=1e-3
//
// Algebraic restructuring (R5): out = BN(P@W_re)@V collapses to
//   out[n][d] = sum_m P[n][m] * M2[m][d] + cv[d]
//   M2[m][d]  = sum_p W_re[m][p] * G[p] * V[p][d]      (12.9 GF, batched bh)
//   cv[d]     = sum_p Cc[p] * V[p][d]
// R26: restore R24 best-known config (142.37 us). conv __launch_bounds__(256,2)
//      (measured optimum: cap=128/2-block beats uncapped-132 @ 9.8% occ and
//      natural-44 alike); attn R22 config (512 blocks x 128 rows, ones-MFMA
//      rowsum, single-buffer P, exp2 softmax).

typedef __attribute__((ext_vector_type(4))) float f32x4;
typedef __bf16 __attribute__((ext_vector_type(8))) bf16x8;
typedef unsigned short u16x8 __attribute__((ext_vector_type(8)));
typedef unsigned int u32x4 __attribute__((ext_vector_type(4)));

__device__ __forceinline__ unsigned short f2bf(float x){
  unsigned u = __builtin_bit_cast(unsigned, x);
  u += 0x7fffu + ((u >> 16) & 1u);          // round-to-nearest-even
  return (unsigned short)(u >> 16);
}

// compiler-lowered conversion (fuses to v_cvt_pk_bf16_f32 for pairs)
__device__ __forceinline__ unsigned short f2bfc(float x){
  __hip_bfloat16 h = __float2bfloat16(x);
  return __builtin_bit_cast(unsigned short, h);
}

__device__ __forceinline__ float bf2f(unsigned short u){
  unsigned v = (unsigned)u << 16;
  return __builtin_bit_cast(float, v);
}

__device__ __forceinline__ f32x4 mfma16(bf16x8 a, bf16x8 b, f32x4 c){
  return __builtin_amdgcn_mfma_f32_16x16x32_bf16(a, b, c, 0, 0, 0);
}

__device__ __forceinline__ bf16x8 ld8(const unsigned short* p){
  return *reinterpret_cast<const bf16x8*>(p);
}

// ---------------------------------------------------------------------------
// Prep: Wre_rm[m][p] = bf16(w_re[m][p]) (coalesced cast);
//       G[p] = gamma*rsqrt(var+eps); Cc=(b_re-mean)*G+beta; CoverG=Cc/G
// ---------------------------------------------------------------------------
__global__ void prep_kernel(const float* __restrict__ w_re, const float* __restrict__ b_re,
                            const float* __restrict__ gma, const float* __restrict__ beta,
                            const float* __restrict__ mean, const float* __restrict__ var,
                            unsigned short* __restrict__ Wre_rm,
                            float* __restrict__ G, float* __restrict__ Cc,
                            float* __restrict__ CoverG)
{
  int idx = blockIdx.x * 256 + threadIdx.x;
  if (idx < 1024*1024){
    Wre_rm[idx] = f2bf(w_re[idx]);
  } else if (idx < 1024*1024 + 1024){
    int p = idx - 1024*1024;
    float g = gma[p] * rsqrtf(var[p] + 1e-3f);
    float cc = (b_re[p] - mean[p]) * g + beta[p];
    G[p] = g;
    Cc[p] = cc;
    CoverG[p] = cc / g;
  }
}

// ---------------------------------------------------------------------------
// Wpt[o][i] = bf16(w_proj[i][o]) via LDS 64x64 tiles (coalesced both sides)
// ---------------------------------------------------------------------------
__global__ __launch_bounds__(256) void wpt_kernel(const float* __restrict__ wp,
                                                  unsigned short* __restrict__ Wpt)
{
  __shared__ float t[64][65];
  const int i0 = blockIdx.x * 64, o0 = blockIdx.y * 64;
  const int r = threadIdx.x >> 6;        // 0..3
  const int c = threadIdx.x & 63;        // 0..63
#pragma unroll
  for (int rep = 0; rep < 16; ++rep){
    int row = rep*4 + r;
    t[row][c] = wp[(size_t)(i0 + row)*768 + o0 + c];
  }
  __syncthreads();
#pragma unroll
  for (int rep = 0; rep < 16; ++rep){
    int orow = rep*4 + r;
    Wpt[(size_t)(o0 + orow)*768 + i0 + c] = f2bf(t[c][orow]);
  }
}

// ---------------------------------------------------------------------------
// Conv 3x3 SAME (R17 structure); row-per-thread, 16 tokens/block, NO LDS.
// __launch_bounds__(256,2) is the measured optimum for the register knob.
// Interleaved convert-and-pack keeps live range small. Weights SGPR-resident.
// ---------------------------------------------------------------------------
__global__ __launch_bounds__(256, 2) void conv_kernel(
    const float* __restrict__ q, const float* __restrict__ k,
    const float* __restrict__ v,
    const float* __restrict__ wq, const float* __restrict__ wk,
    const float* __restrict__ wv,
    const float* __restrict__ G,
    unsigned short* __restrict__ qh, unsigned short* __restrict__ kh,
    unsigned short* __restrict__ vh)
{
  const int tb = blockIdx.x;         // 0..511 (16 tokens each)
  const int which = blockIdx.y;      // 0=q 1=k 2=v
  const float* x = (which == 0) ? q : (which == 1) ? k : v;
  const float* w = (which == 0) ? wq : (which == 1) ? wk : wv;
  unsigned short* dst = (which == 0) ? qh : (which == 1) ? kh : vh;

  // weights -> SGPRs (uniform pointer, compile-time offsets => s_load)
  float wreg[81];
#pragma unroll
  for (int i = 0; i < 81; ++i) wreg[i] = w[i];

  const int tid = threadIdx.x;
  const int ti = tid >> 4;           // token in block 0..15
  const int r  = tid & 15;           // output row 0..15
  const int token = tb*16 + ti;
  const float* xt = x + (size_t)token*768;

  const int rm = (r > 0)  ? r-1 : 0;
  const int rp = (r < 15) ? r+1 : 15;
  const float mm = (r > 0)  ? 1.f : 0.f;
  const float mp = (r < 15) ? 1.f : 0.f;

  f32x4 Rm[12], R0[12], Rp[12];
#pragma unroll
  for (int j = 0; j < 12; ++j){
    Rm[j] = *reinterpret_cast<const f32x4*>(xt + rm*48 + j*4);
    R0[j] = *reinterpret_cast<const f32x4*>(xt + r *48 + j*4);
    Rp[j] = *reinterpret_cast<const f32x4*>(xt + rp*48 + j*4);
  }
#pragma unroll
  for (int j = 0; j < 12; ++j){
    Rm[j] = Rm[j] * mm;
    Rp[j] = Rp[j] * mp;
  }

  const float gs = (which == 2) ? G[token & 1023] : 1.f;

  unsigned int pk[24];               // 48 u16 packed as 24 dwords

#pragma unroll
  for (int c = 0; c < 16; ++c){
    float a0 = 0.f, a1 = 0.f, a2 = 0.f;
#pragma unroll
    for (int dc = 0; dc < 3; ++dc){
      const int cc = c + dc - 1;
      if (cc < 0 || cc > 15) continue;         // static skip (halo)
#pragma unroll
      for (int ci = 0; ci < 3; ++ci){
        const int e = cc*3 + ci;
        const float xm = Rm[e >> 2][e & 3];
        const float x0 = R0[e >> 2][e & 3];
        const float xp = Rp[e >> 2][e & 3];
        const int w0 = (0*3 + dc)*9 + ci*3;
        const int w1 = (1*3 + dc)*9 + ci*3;
        const int w2 = (2*3 + dc)*9 + ci*3;
        a0 += xm*wreg[w0+0] + x0*wreg[w1+0] + xp*wreg[w2+0];
        a1 += xm*wreg[w0+1] + x0*wreg[w1+1] + xp*wreg[w2+1];
        a2 += xm*wreg[w0+2] + x0*wreg[w1+2] + xp*wreg[w2+2];
      }
    }
    const unsigned short b0 = f2bf(a0*gs), b1 = f2bf(a1*gs), b2 = f2bf(a2*gs);
    const int f = c*3;               // 0,3,6,...,45 (u16 index in [0,48))
    if ((f & 1) == 0){
      pk[f>>1] = (unsigned)b0 | ((unsigned)b1 << 16);
      pk[(f+2)>>1] = (unsigned)b2;                     // low half; high set later
    } else {
      pk[f>>1] |= ((unsigned)b0 << 16);
      pk[(f+1)>>1] = (unsigned)b1 | ((unsigned)b2 << 16);
    }
  }

  const int b = token >> 10, n = token & 1023;
  const int h = r >> 1;
  unsigned short* dstp = dst + ((size_t)(b*8 + h)*1024 + n)*96 + (r & 1)*48;
#pragma unroll
  for (int j = 0; j < 6; ++j){
    u32x4 sv;
#pragma unroll
    for (int e = 0; e < 4; ++e) sv[e] = pk[j*4 + e];
    *reinterpret_cast<u32x4*>(dstp + j*8) = sv;        // 8 u16 = 16 B per store
  }
}

// ---------------------------------------------------------------------------
// Transpose vh[bh][n][96] -> vtg[bh][d][n] via LDS tile; also accumulates
// cvpart[chunk][bh][d]. Grid (8 n-chunks, 64 bh).
// ---------------------------------------------------------------------------
__global__ __launch_bounds__(256) void vt_kernel(const unsigned short* __restrict__ vh,
                                                 const float* __restrict__ CoverG,
                                                 unsigned short* __restrict__ vtg,
                                                 float* __restrict__ cvpart)
{
  __shared__ unsigned short t[96*136];       // row d: stride 136 (272 B, 16B-aligned, odd*16B)
  const int chunk = blockIdx.x;              // 0..7
  const int bh = blockIdx.y;                 // 0..63
  const int n0 = chunk*128;
  const int tid = threadIdx.x;

  const unsigned short* src = vh + ((size_t)bh*1024 + n0)*96;
#pragma unroll
  for (int it = 0; it < 6; ++it){
    int idx = it*256 + tid;                  // 0..1535
    int row = idx / 12, v = idx - row*12;    // row 0..127, v 0..11
    u16x8 xv = *reinterpret_cast<const u16x8*>(src + row*96 + v*8);
#pragma unroll
    for (int j = 0; j < 8; ++j) t[(v*8 + j)*136 + row] = xv[j];
  }
  __syncthreads();

  unsigned short* dstp = vtg + (size_t)bh*96*1024 + n0;
#pragma unroll
  for (int it = 0; it < 6; ++it){
    int idx = it*256 + tid;                  // 0..1535
    int d = idx >> 4, ch = idx & 15;         // d 0..95, ch 0..15
    u16x8 xv = *reinterpret_cast<const u16x8*>(&t[d*136 + ch*8]);
    *reinterpret_cast<u16x8*>(dstp + (size_t)d*1024 + ch*8) = xv;

    // cv partial: this thread holds V[d][n0+ch*8 .. +8)
    float s = 0.f;
#pragma unroll
    for (int j = 0; j < 8; ++j) s += CoverG[n0 + ch*8 + j] * bf2f(xv[j]);
#pragma unroll
    for (int o = 1; o < 16; o <<= 1) s += __shfl_xor(s, o);   // reduce 16-lane group
    if (ch == 0) cvpart[((size_t)chunk*64 + bh)*96 + d] = s;
  }
}

// ---------------------------------------------------------------------------
// M2t[bh][d][m] = sum_p Wre_rm[m][p] * vtg[bh][d][p]   (K = 1024 over p)
// R11: block-staged double-buffered W-tile (128x32) + V-tile (96x32).
// ---------------------------------------------------------------------------
__global__ __launch_bounds__(256, 2) void m2_kernel(
    const unsigned short* __restrict__ Wre_rm, const unsigned short* __restrict__ vtg,
    unsigned short* __restrict__ M2t)
{
  constexpr int WST = 40;   // W-tile row stride (u16): 128 x 40
  constexpr int VST = 40;   // V-tile row stride (u16): 96 x 40
  __shared__ __align__(16) unsigned short Wst[2][128*WST];   // 20480 B
  __shared__ __align__(16) unsigned short Vst[2][96*VST];    // 15360 B -> 35840 B

  const int id = blockIdx.x;             // 0..511
  const int xcd = id & 7, slot = id >> 3;
  const int mtile = slot & 7;            // 0..7
  const int bh = xcd + ((slot >> 3) << 3);
  const int tid = threadIdx.x;
  const int w = tid >> 6, lane = tid & 63, lh = lane >> 4, lm = lane & 15;
  const int m0 = mtile*128;              // block's m-base
  const int mw = w*32;                   // wave's m offset in tile

  const unsigned short* vb = vtg + (size_t)bh * 96 * 1024;
  const unsigned short* Wb = Wre_rm + (size_t)m0 * 1024;

  const int cr = tid >> 2, cc0 = (tid & 3)*8;
  const bool has3 = (tid < 128);

  f32x4 acc[2][6];
#pragma unroll
  for (int rt = 0; rt < 2; ++rt)
#pragma unroll
    for (int dt = 0; dt < 6; ++dt)
      acc[rt][dt] = f32x4{0.f, 0.f, 0.f, 0.f};

  // --- prologue: stage p-tile 0 into buffer 0 ---
  u16x8 g0, g1, g2, g3;
  g0 = *reinterpret_cast<const u16x8*>(Wb + (size_t)cr*1024 + cc0);
  g1 = *reinterpret_cast<const u16x8*>(Wb + (size_t)(64 + cr)*1024 + cc0);
  g2 = *reinterpret_cast<const u16x8*>(vb + (size_t)cr*1024 + cc0);
  if (has3) g3 = *reinterpret_cast<const u16x8*>(vb + (size_t)(64 + cr)*1024 + cc0);
  *reinterpret_cast<u16x8*>(&Wst[0][cr*WST + cc0]) = g0;
  *reinterpret_cast<u16x8*>(&Wst[0][(64 + cr)*WST + cc0]) = g1;
  *reinterpret_cast<u16x8*>(&Vst[0][cr*VST + cc0]) = g2;
  if (has3) *reinterpret_cast<u16x8*>(&Vst[0][(64 + cr)*VST + cc0]) = g3;
  __syncthreads();

  for (int ks = 0; ks < 32; ++ks){
    const int cur = ks & 1;

    if (ks < 31){
      const int p0 = (ks+1)*32;
      g0 = *reinterpret_cast<const u16x8*>(Wb + (size_t)cr*1024 + p0 + cc0);
      g1 = *reinterpret_cast<const u16x8*>(Wb + (size_t)(64 + cr)*1024 + p0 + cc0);
      g2 = *reinterpret_cast<const u16x8*>(vb + (size_t)cr*1024 + p0 + cc0);
      if (has3) g3 = *reinterpret_cast<const u16x8*>(vb + (size_t)(64 + cr)*1024 + p0 + cc0);
    }

    const unsigned short* Wc = &Wst[cur][0];
    const unsigned short* Vc = &Vst[cur][0];
    bf16x8 aW0 = ld8(Wc + (mw + lm)*WST + lh*8);
    bf16x8 aW1 = ld8(Wc + (mw + 16 + lm)*WST + lh*8);
#pragma unroll
    for (int dt = 0; dt < 6; ++dt){
      bf16x8 bV = ld8(Vc + (dt*16 + lm)*VST + lh*8);
      acc[0][dt] = mfma16(aW0, bV, acc[0][dt]);
      acc[1][dt] = mfma16(aW1, bV, acc[1][dt]);
    }

    if (ks < 31){
      const int nxt = cur ^ 1;
      *reinterpret_cast<u16x8*>(&Wst[nxt][cr*WST + cc0]) = g0;
      *reinterpret_cast<u16x8*>(&Wst[nxt][(64 + cr)*WST + cc0]) = g1;
      *reinterpret_cast<u16x8*>(&Vst[nxt][cr*VST + cc0]) = g2;
      if (has3) *reinterpret_cast<u16x8*>(&Vst[nxt][(64 + cr)*VST + cc0]) = g3;
    }
    __syncthreads();
  }

#pragma unroll
  for (int rt = 0; rt < 2; ++rt)
#pragma unroll
    for (int dt = 0; dt < 6; ++dt)
#pragma unroll
      for (int rg = 0; rg < 4; ++rg){
        int m = m0 + mw + rt*16 + lh*4 + rg;
        int d = dt*16 + lm;
        M2t[((size_t)bh*96 + d)*1024 + m] = f2bf(acc[rt][dt][rg]);
      }
}

// ---------------------------------------------------------------------------
// Fused attention (R22 config): 512 blocks (2/CU), 128 q-rows/block,
// 32 rows/wave. Block-staged K/M2 tiles (dbuf); single-buffered wave-private
// P stage; rowsum via ones-B MFMA; exp2 softmax; cv from 8 partials.
// ---------------------------------------------------------------------------
__global__ __launch_bounds__(256, 2) void attn_kernel(
    const unsigned short* __restrict__ qh, const unsigned short* __restrict__ kh,
    const unsigned short* __restrict__ M2t, const float* __restrict__ cvpart,
    unsigned short* __restrict__ xh)
{
  constexpr int KST = 104;   // K-tile row stride (u16): 32 x 104
  constexpr int MST = 40;    // M-tile row stride (u16): 96 x 40
  constexpr int PST = 40;    // P stage row stride (u16): 32 x 40 per wave
  __shared__ __align__(16) unsigned short Kst[2][32*KST];    // 13312 B
  __shared__ __align__(16) unsigned short Mst[2][96*MST];    // 15360 B
  __shared__ __align__(16) unsigned short Pst[4][32*PST];    // 10240 B -> 38912 B

  const int id = blockIdx.x;             // 0..511
  const int xcd = id & 7, slot = id >> 3;
  const int chunk = slot & 7;            // 128-row chunk
  const int bh = xcd + ((slot >> 3) << 3);
  const int tid = threadIdx.x;
  const int w = tid >> 6;                // 0..3
  const int lane = tid & 63;
  const int lh = lane >> 4;              // 0..3
  const int lm = lane & 15;              // 0..15
  const int q0 = chunk*128 + w*32;       // this wave's 32 q-rows

  const unsigned short* Qb = qh + (size_t)bh * 1024 * 96;
  const unsigned short* Kb = kh + (size_t)bh * 1024 * 96;
  const unsigned short* Mb = M2t + (size_t)bh * 96 * 1024;

  const int kr0 = tid/12,  kc0 = (tid%12)*8;
  const bool c1K = (tid < 128);
  const int t1 = tid + 256;
  const int kr1 = c1K ? t1/12 : 0,  kc1 = c1K ? (t1%12)*8 : 0;
  const int md1 = c1K ? 0 : (tid-128)>>2, mc1 = c1K ? 0 : ((tid-128)&3)*8;
  const int md2 = (tid+128)>>2, mc2 = ((tid+128)&3)*8;

  bf16x8 aq[2][3];
#pragma unroll
  for (int rt = 0; rt < 2; ++rt)
#pragma unroll
    for (int kq = 0; kq < 3; ++kq)
      aq[rt][kq] = ld8(Qb + (size_t)(q0 + rt*16 + lm)*96 + kq*32 + lh*8);

  // ones B-fragment for the rowsum MFMA (bf16 1.0 = 0x3F80)
  u16x8 onesU = {0x3F80, 0x3F80, 0x3F80, 0x3F80, 0x3F80, 0x3F80, 0x3F80, 0x3F80};
  const bf16x8 kOnes = __builtin_bit_cast(bf16x8, onesU);

  f32x4 out[2][6];
#pragma unroll
  for (int rt = 0; rt < 2; ++rt)
#pragma unroll
    for (int dt = 0; dt < 6; ++dt) out[rt][dt] = f32x4{0.f, 0.f, 0.f, 0.f};
  f32x4 outS[2] = {f32x4{0.f,0.f,0.f,0.f}, f32x4{0.f,0.f,0.f,0.f}};

  // SCALE * log2(e): exp(x*SCALE) = exp2(x*SCALE2), native v_exp_f32
  const float SCALE2 = 0.14724404930696491f;

  u16x8 g0, g1, g2;
  {
    g0 = *reinterpret_cast<const u16x8*>(Kb + (size_t)kr0*96 + kc0);
    g1 = c1K ? *reinterpret_cast<const u16x8*>(Kb + (size_t)kr1*96 + kc1)
             : *reinterpret_cast<const u16x8*>(Mb + (size_t)md1*1024 + mc1);
    g2 = *reinterpret_cast<const u16x8*>(Mb + (size_t)md2*1024 + mc2);
    *reinterpret_cast<u16x8*>(&Kst[0][kr0*KST + kc0]) = g0;
    if (c1K) *reinterpret_cast<u16x8*>(&Kst[0][kr1*KST + kc1]) = g1;
    else     *reinterpret_cast<u16x8*>(&Mst[0][md1*MST + mc1]) = g1;
    *reinterpret_cast<u16x8*>(&Mst[0][md2*MST + mc2]) = g2;
  }
  __syncthreads();

  for (int kt = 0; kt < 32; ++kt){
    const int cur = kt & 1;

    if (kt < 31){
      const int kb = (kt+1)*32;
      g0 = *reinterpret_cast<const u16x8*>(Kb + (size_t)(kb + kr0)*96 + kc0);
      g1 = c1K ? *reinterpret_cast<const u16x8*>(Kb + (size_t)(kb + kr1)*96 + kc1)
               : *reinterpret_cast<const u16x8*>(Mb + (size_t)md1*1024 + kb + mc1);
      g2 = *reinterpret_cast<const u16x8*>(Mb + (size_t)md2*1024 + kb + mc2);
    }

    const unsigned short* Kc = &Kst[cur][0];
    f32x4 sacc[2][2];
    sacc[0][0] = f32x4{0.f,0.f,0.f,0.f}; sacc[0][1] = f32x4{0.f,0.f,0.f,0.f};
    sacc[1][0] = f32x4{0.f,0.f,0.f,0.f}; sacc[1][1] = f32x4{0.f,0.f,0.f,0.f};
#pragma unroll
    for (int kq = 0; kq < 3; ++kq){
      bf16x8 bk0 = ld8(Kc + lm*KST        + kq*32 + lh*8);
      bf16x8 bk1 = ld8(Kc + (16 + lm)*KST + kq*32 + lh*8);
      sacc[0][0] = mfma16(aq[0][kq], bk0, sacc[0][0]);
      sacc[0][1] = mfma16(aq[0][kq], bk1, sacc[0][1]);
      sacc[1][0] = mfma16(aq[1][kq], bk0, sacc[1][0]);
      sacc[1][1] = mfma16(aq[1][kq], bk1, sacc[1][1]);
    }

    // exp2 (unnormalized softmax) -> per-wave private P stage (single buffer)
    unsigned short* Pc = &Pst[w][0];
#pragma unroll
    for (int rt = 0; rt < 2; ++rt)
#pragma unroll
      for (int nt = 0; nt < 2; ++nt)
#pragma unroll
        for (int rg = 0; rg < 4; ++rg){
          float e = __builtin_amdgcn_exp2f(sacc[rt][nt][rg] * SCALE2);
          Pc[(rt*16 + lh*4 + rg)*PST + nt*16 + lm] = f2bfc(e);
        }

    bf16x8 ap0 = ld8(Pc + lm*PST        + lh*8);
    bf16x8 ap1 = ld8(Pc + (16 + lm)*PST + lh*8);

    // PV + rowsum (ones-B MFMA rides the matrix pipe)
    const unsigned short* Mc = &Mst[cur][0];
#pragma unroll
    for (int dt = 0; dt < 6; ++dt){
      bf16x8 bm = ld8(Mc + (dt*16 + lm)*MST + lh*8);
      out[0][dt] = mfma16(ap0, bm, out[0][dt]);
      out[1][dt] = mfma16(ap1, bm, out[1][dt]);
    }
    outS[0] = mfma16(ap0, kOnes, outS[0]);
    outS[1] = mfma16(ap1, kOnes, outS[1]);

    if (kt < 31){
      const int nxt = cur ^ 1;
      *reinterpret_cast<u16x8*>(&Kst[nxt][kr0*KST + kc0]) = g0;
      if (c1K) *reinterpret_cast<u16x8*>(&Kst[nxt][kr1*KST + kc1]) = g1;
      else     *reinterpret_cast<u16x8*>(&Mst[nxt][md1*MST + mc1]) = g1;
      *reinterpret_cast<u16x8*>(&Mst[nxt][md2*MST + mc2]) = g2;
    }
    __syncthreads();
  }

  // rowsum lives in outS: every lane's column holds the same row-sum
  f32x4 rinv[2];
#pragma unroll
  for (int rt = 0; rt < 2; ++rt)
#pragma unroll
    for (int rg = 0; rg < 4; ++rg)
      rinv[rt][rg] = 1.f / outS[rt][rg];

#pragma unroll
  for (int dt = 0; dt < 6; ++dt){
    float cvv = 0.f;
#pragma unroll
    for (int ch = 0; ch < 8; ++ch)
      cvv += cvpart[((size_t)ch*64 + bh)*96 + dt*16 + lm];
#pragma unroll
    for (int rt = 0; rt < 2; ++rt)
#pragma unroll
      for (int rg = 0; rg < 4; ++rg){
        int row = q0 + rt*16 + lh*4 + rg;
        xh[((size_t)bh*1024 + row)*96 + dt*16 + lm] =
            f2bfc(out[rt][dt][rg]*rinv[rt][rg] + cvv);
      }
  }
}

// ---------------------------------------------------------------------------
// Projection (R10): out[t][o] = sum_i xh[t][i]*Wpt[o][i] + b_proj[o].
// ---------------------------------------------------------------------------
__global__ __launch_bounds__(256, 2) void proj_kernel(
    const unsigned short* __restrict__ xh, const unsigned short* __restrict__ Wpt,
    const float* __restrict__ b_proj, float* __restrict__ out)
{
  constexpr int BST = 40;    // B-tile row stride (u16): 96 x 40
  __shared__ __align__(16) unsigned short Bst[2][96*BST];    // 15360 B

  const int mb = blockIdx.x;        // 0..63 -> 128 tokens
  const int nb = blockIdx.y;        // 0..7  -> 96 outputs
  const int tid = threadIdx.x;
  const int w = tid >> 6, lane = tid & 63, lh = lane >> 4, lm = lane & 15;
  const int t0 = mb*128 + w*32;
  const int o0 = nb*96;

  const int br0 = tid >> 2,          bc0 = (tid & 3)*8;
  const bool has1 = (tid < 128);
  const int br1 = (tid + 256) >> 2,  bc1 = ((tid + 256) & 3)*8;
  const unsigned short* Bsrc = Wpt + (size_t)o0*768;

  f32x4 acc[2][6];
#pragma unroll
  for (int rt = 0; rt < 2; ++rt)
#pragma unroll
    for (int nt = 0; nt < 6; ++nt) acc[rt][nt] = f32x4{0.f, 0.f, 0.f, 0.f};

  const int tok0 = t0 + lm, tok1 = t0 + 16 + lm;
  const int b0 = tok0 >> 10, n0_ = tok0 & 1023;
  const int b1 = tok1 >> 10, n1_ = tok1 & 1023;

  u16x8 g0, g1;
  g0 = *reinterpret_cast<const u16x8*>(Bsrc + (size_t)br0*768 + bc0);
  if (has1) g1 = *reinterpret_cast<const u16x8*>(Bsrc + (size_t)br1*768 + bc1);
  *reinterpret_cast<u16x8*>(&Bst[0][br0*BST + bc0]) = g0;
  if (has1) *reinterpret_cast<u16x8*>(&Bst[0][br1*BST + bc1]) = g1;
  __syncthreads();

  for (int kt = 0; kt < 24; ++kt){
    const int cur = kt & 1;

    if (kt < 23){
      const int ib = (kt+1)*32;
      g0 = *reinterpret_cast<const u16x8*>(Bsrc + (size_t)br0*768 + ib + bc0);
      if (has1) g1 = *reinterpret_cast<const u16x8*>(Bsrc + (size_t)br1*768 + ib + bc1);
    }

    const int h = kt/3, d0 = (kt - h*3)*32 + lh*8;
    bf16x8 a0 = ld8(xh + ((size_t)(b0*8 + h)*1024 + n0_)*96 + d0);
    bf16x8 a1 = ld8(xh + ((size_t)(b1*8 + h)*1024 + n1_)*96 + d0);

    const unsigned short* Bc = &Bst[cur][0];
#pragma unroll
    for (int nt = 0; nt < 6; ++nt){
      bf16x8 bv = ld8(Bc + (nt*16 + lm)*BST + lh*8);
      acc[0][nt] = mfma16(a0, bv, acc[0][nt]);
      acc[1][nt] = mfma16(a1, bv, acc[1][nt]);
    }

    if (kt < 23){
      const int nxt = cur ^ 1;
      *reinterpret_cast<u16x8*>(&Bst[nxt][br0*BST + bc0]) = g0;
      if (has1) *reinterpret_cast<u16x8*>(&Bst[nxt][br1*BST + bc1]) = g1;
    }
    __syncthreads();
  }

#pragma unroll
  for (int nt = 0; nt < 6; ++nt){
    int o = o0 + nt*16 + lm;
    float bias = b_proj[o];
#pragma unroll
    for (int rt = 0; rt < 2; ++rt)
#pragma unroll
      for (int rg = 0; rg < 4; ++rg)
        out[(size_t)(t0 + rt*16 + lh*4 + rg)*768 + o] = acc[rt][nt][rg] + bias;
  }
}

// ---------------------------------------------------------------------------
extern "C" void kernel_launch(void* const* d_in, const int* in_sizes, int n_in,
                              void* d_out, int out_size, void* d_ws, size_t ws_size,
                              hipStream_t stream)
{
  (void)in_sizes; (void)n_in; (void)out_size; (void)ws_size;
  const float* q      = (const float*)d_in[0];
  const float* k      = (const float*)d_in[1];
  const float* v      = (const float*)d_in[2];
  const float* wq     = (const float*)d_in[3];
  const float* wk     = (const float*)d_in[4];
  const float* wv     = (const float*)d_in[5];
  const float* w_re   = (const float*)d_in[6];
  const float* b_re   = (const float*)d_in[7];
  const float* gma    = (const float*)d_in[8];
  const float* beta   = (const float*)d_in[9];
  const float* mean   = (const float*)d_in[10];
  const float* var    = (const float*)d_in[11];
  const float* w_proj = (const float*)d_in[12];
  const float* b_proj = (const float*)d_in[13];
  float* out = (float*)d_out;

  // ws layout (bytes): total ~66.5 MB. vh aliases the xh slot (vh is dead
  // before attn writes xh).
  char* ws = (char*)d_ws;
  unsigned short* qh     = (unsigned short*)(ws + 0);          // 12,582,912
  unsigned short* kh     = (unsigned short*)(ws + 12582912);   // 12,582,912
  unsigned short* vtg    = (unsigned short*)(ws + 25165824);   // 12,582,912
  unsigned short* xh     = (unsigned short*)(ws + 37748736);   // 12,582,912
  unsigned short* vh     = xh;                                 // alias (dead before attn)
  unsigned short* Wre_rm = (unsigned short*)(ws + 50331648);   //  2,097,152
  unsigned short* Wpt    = (unsigned short*)(ws + 52428800);   //  1,179,648
  unsigned short* M2t    = (unsigned short*)(ws + 53608448);   // 12,582,912
  float*          G      = (float*)(ws + 66191360);            //      4,096
  float*          Cc     = (float*)(ws + 66195456);            //      4,096
  float*          CoverG = (float*)(ws + 66199552);            //      4,096
  float*          cvpart = (float*)(ws + 66203648);            //    196,608

  prep_kernel<<<dim3(4100), dim3(256), 0, stream>>>(w_re, b_re, gma, beta, mean, var,
                                                    Wre_rm, G, Cc, CoverG);
  wpt_kernel<<<dim3(12, 12), dim3(256), 0, stream>>>(w_proj, Wpt);
  conv_kernel<<<dim3(512, 3), dim3(256), 0, stream>>>(q, k, v, wq, wk, wv, G, qh, kh, vh);
  vt_kernel<<<dim3(8, 64), dim3(256), 0, stream>>>(vh, CoverG, vtg, cvpart);
  m2_kernel<<<dim3(512), dim3(256), 0, stream>>>(Wre_rm, vtg, M2t);
  attn_kernel<<<dim3(512), dim3(256), 0, stream>>>(qh, kh, M2t, cvpart, xh);
  proj_kernel<<<dim3(64, 8), dim3(256), 0, stream>>>(xh, Wpt, b_proj, out);
}